// Round 2
// baseline (168.141 us; speedup 1.0000x reference)
//
#include <hip/hip_runtime.h>
#include <cstdint>

#define DIMD 1024
#define NROWS 8192
#define KDIM 2048   // 2*DIM

typedef unsigned short u16;
typedef __bf16 bf16x8 __attribute__((ext_vector_type(8)));
typedef float f32x4 __attribute__((ext_vector_type(4)));

__device__ __forceinline__ u16 f2bf(float f) {
  unsigned u = __builtin_bit_cast(unsigned, f);
  return (u16)((u + 0x7FFFu + ((u >> 16) & 1u)) >> 16);  // RNE
}

// Branch-free exact-enough GELU (A&S 7.1.26 erf, |err| <= 1.5e-7).
__device__ __forceinline__ float gelu_exact(float x) {
  float s = 0.70710678118654752f * x;
  float a = fabsf(s);
  float k = __fdividef(1.0f, fmaf(0.3275911f, a, 1.0f));
  float p = 1.061405429f;
  p = fmaf(p, k, -1.453152027f);
  p = fmaf(p, k, 1.421413741f);
  p = fmaf(p, k, -0.284496736f);
  p = fmaf(p, k, 0.254829592f);
  p = p * k;
  float e = __expf(-s * s);
  float erf_s = copysignf(fmaf(-p, e, 1.0f), s);
  return 0.5f * x * (1.0f + erf_s);
}

// ---------------------------------------------------------------------------
// Fused pre-kernel: conv(3x5)+bias+gelu -> x2 bf16, and w2 fp32->bf16 cast.
// (unchanged)
// ---------------------------------------------------------------------------
__global__ __launch_bounds__(256) void pre_kernel(
    const float* __restrict__ ifeats, const float* __restrict__ tn,
    const float* __restrict__ ta, const float* __restrict__ cw,
    const float* __restrict__ cb, const float* __restrict__ w2,
    u16* __restrict__ x2, u16* __restrict__ w2b) {
  const int b = blockIdx.x;
  const int t = threadIdx.x;
  if (b < NROWS) {
    __shared__ float si[DIMD], sn[DIMD], sa[DIMD];
    ((float4*)si)[t] = ((const float4*)(ifeats + (size_t)b * DIMD))[t];
    ((float4*)sn)[t] = ((const float4*)tn)[t];
    ((float4*)sa)[t] = ((const float4*)ta)[t];
    __syncthreads();
    const int c = t >> 7;
    const int w0 = (t & 127) << 3;
    float cwn[5], cwa[5], cwi[5];
#pragma unroll
    for (int k = 0; k < 5; ++k) {
      cwn[k] = cw[c * 15 + k];
      cwa[k] = cw[c * 15 + 5 + k];
      cwi[k] = cw[c * 15 + 10 + k];
    }
    const float bias = cb[c];
    float wn[12], wa[12], wi[12];
#pragma unroll
    for (int j = 0; j < 12; ++j) {
      int wp = w0 - 2 + j;
      bool ok = (wp >= 0) && (wp < DIMD);
      wn[j] = ok ? sn[wp] : 0.f;
      wa[j] = ok ? sa[wp] : 0.f;
      wi[j] = ok ? si[wp] : 0.f;
    }
    union { u16 o[8]; uint4 u; } pk;
#pragma unroll
    for (int s = 0; s < 8; ++s) {
      float x = bias;
#pragma unroll
      for (int k = 0; k < 5; ++k) {
        x = fmaf(cwn[k], wn[s + k], x);
        x = fmaf(cwa[k], wa[s + k], x);
        x = fmaf(cwi[k], wi[s + k], x);
      }
      pk.o[s] = f2bf(gelu_exact(x));
    }
    *(uint4*)(x2 + (size_t)b * KDIM + c * DIMD + w0) = pk.u;
  } else {
    const int t2 = (b - NROWS) * 256 + t;
    const float4* p = (const float4*)(w2 + (size_t)t2 * 8);
    float4 a = p[0], bb = p[1];
    union { u16 o[8]; uint4 v; } pk;
    pk.o[0] = f2bf(a.x);  pk.o[1] = f2bf(a.y);  pk.o[2] = f2bf(a.z);  pk.o[3] = f2bf(a.w);
    pk.o[4] = f2bf(bb.x); pk.o[5] = f2bf(bb.y); pk.o[6] = f2bf(bb.z); pk.o[7] = f2bf(bb.w);
    *(uint4*)(w2b + (size_t)t2 * 8) = pk.v;
  }
}

// ---------------------------------------------------------------------------
// GEMM v4: single big compute phase per K-tile + counted vmcnt.
//   128x128 block tile, 4 waves (256 thr), per-wave 64x64 (4x4 acc) ->
//   32 FLOP/LDS-byte (LDS-BW balanced vs MFMA pipe; r0's 4x2 was 21 FLOP/B,
//   capped at ~1.4 PF by LDS).
//   BK=32, 3-deep LDS rotation (48 KB -> 3 blocks/CU, 12 waves/CU).
//   Per K-tile (64 iters): ONE compute phase (8 ds_read_b128 + 16 MFMA),
//   TWO raw barriers (r1's four tiny phases per tile were barrier-swamped):
//     B1 (top)  : all waves done compute(t-1) -> buf[(t+2)%3] is free
//     stage(t+2): 4 gl_lds16/wave into freed buffer
//     vmcnt(8)  : drain own tile-t loads, keep t+1/t+2 (8) in flight
//     B2        : all waves drained tile t -> data-ready
//   Tile t+2 issued at iter t, drained at iter t+2 -> 2-iteration slack
//   (~700 cyc) >= HBM latency. sched_barrier(0) after each raw barrier
//   prevents LDS-op hoisting across (raw s_barrier is not a compiler fence).
// Swizzle (verified 0 conflicts in r1): LDS[row][c] = global chunk
//   c ^ ((row>>1)&3); read chunk = quad ^ ((r16>>1)&3).
// ---------------------------------------------------------------------------
__device__ __forceinline__ void gl_lds16(const u16* g, u16* l) {
  __builtin_amdgcn_global_load_lds(
      (__attribute__((address_space(1))) void*)g,
      (__attribute__((address_space(3))) void*)l, 16, 0, 0);
}

#define BK 32       // u16 per row per K-tile
#define NTILE 64    // KDIM / BK

__global__ __launch_bounds__(256, 3) void gemm_bt(
    const u16* __restrict__ A,      // x2 bf16 [8192, 2048]
    const u16* __restrict__ B,      // w2 bf16 [1024, 2048]
    const float* __restrict__ ifeats,
    const float* __restrict__ b2,
    float* __restrict__ out) {
  constexpr int K = KDIM;
  __shared__ __align__(16) u16 sA[3][128 * BK];  // 3 x 8 KB
  __shared__ __align__(16) u16 sB[3][128 * BK];  // 3 x 8 KB; 48 KB total

  const int tid = threadIdx.x;
  const int wv = tid >> 6;         // wave 0..3
  const int lane = tid & 63;
  // XCD-aware swizzle: xcd owns M-strips -> A-panel L2 reuse.
  const int id = blockIdx.x;       // 0..511
  const int xcd = id & 7;
  const int s_ = id >> 3;          // 0..63
  const int i0 = (xcd * 8 + (s_ >> 3)) * 128;
  const int j0 = (s_ & 7) * 128;

  const int wm = (wv & 1) * 64;    // wave tile: 64 (M) x 64 (N)
  const int wn = (wv >> 1) * 64;
  const int quad = lane >> 4;      // k-chunk selector (0..3)
  const int r16 = lane & 15;
  const int csw = (r16 >> 1) & 3;  // read-side chunk swizzle

  // Staging: per tile, A = 128 rows x 64 B = 8 KB = 2 gl_lds16/wave; B same.
  // Wave wv covers rows {u*64 + wv*16 .. +16} for u in {0,1}.
  // Global source pre-swizzled: chunk = (lane&3) ^ ((lane>>3)&3).
  const int srow = lane >> 2;                     // 0..15
  const int schk = (lane & 3) ^ ((lane >> 3) & 3);
  const u16* gA[2];
  const u16* gB[2];
#pragma unroll
  for (int u = 0; u < 2; ++u) {
    gA[u] = A + (size_t)(i0 + u * 64 + wv * 16 + srow) * K + schk * 8;
    gB[u] = B + (size_t)(j0 + u * 64 + wv * 16 + srow) * K + schk * 8;
  }
  const int ldso = wv * 16 * BK;   // wave's slice inside a 64-row unit

  const f32x4 vzero = {0.f, 0.f, 0.f, 0.f};
  f32x4 acc[4][4];
#pragma unroll
  for (int a = 0; a < 4; ++a)
#pragma unroll
    for (int b = 0; b < 4; ++b) acc[a][b] = vzero;

  u16* a0 = (u16*)sA[0]; u16* a1 = (u16*)sA[1]; u16* a2 = (u16*)sA[2];
  u16* b0 = (u16*)sB[0]; u16* b1 = (u16*)sB[1]; u16* b2s = (u16*)sB[2];

  auto issue = [&](u16* bufA, u16* bufB, int t) {
#pragma unroll
    for (int u = 0; u < 2; ++u) {
      gl_lds16(gA[u] + t * BK, bufA + u * 64 * BK + ldso);
      gl_lds16(gB[u] + t * BK, bufB + u * 64 * BK + ldso);
    }
  };

  // Prologue: tiles 0,1 -> bufs 0,1 (4 loads/wave each; 8 outstanding).
  issue(a0, b0, 0);
  issue(a1, b1, 1);

  for (int t = 0; t < NTILE; ++t) {
    __builtin_amdgcn_s_barrier();            // B1: buf[(t+2)%3] free
    __builtin_amdgcn_sched_barrier(0);
    if (t + 2 < NTILE) issue(a2, b2s, t + 2);
    if (t + 2 < NTILE) {
      asm volatile("s_waitcnt vmcnt(8)" ::: "memory");   // drain tile t
    } else if (t + 1 < NTILE) {
      asm volatile("s_waitcnt vmcnt(4)" ::: "memory");
    } else {
      asm volatile("s_waitcnt vmcnt(0)" ::: "memory");
    }
    __builtin_amdgcn_s_barrier();            // B2: tile t data-ready
    __builtin_amdgcn_sched_barrier(0);

    bf16x8 av[4], bv[4];
#pragma unroll
    for (int mt = 0; mt < 4; ++mt)
      av[mt] = *(const bf16x8*)&a0[(wm + mt * 16 + r16) * BK + ((quad ^ csw) << 3)];
#pragma unroll
    for (int nt = 0; nt < 4; ++nt)
      bv[nt] = *(const bf16x8*)&b0[(wn + nt * 16 + r16) * BK + ((quad ^ csw) << 3)];
#pragma unroll
    for (int mt = 0; mt < 4; ++mt)
#pragma unroll
      for (int nt = 0; nt < 4; ++nt)
        acc[mt][nt] = __builtin_amdgcn_mfma_f32_16x16x32_bf16(av[mt], bv[nt], acc[mt][nt], 0, 0, 0);

    // rotate 3-deep buffers
    u16* ta_ = a0; a0 = a1; a1 = a2; a2 = ta_;
    u16* tb_ = b0; b0 = b1; b1 = b2s; b2s = tb_;
  }

  // epilogue: C/D layout col=lane&15, row=quad*4+reg
#pragma unroll
  for (int nt = 0; nt < 4; ++nt) {
    int col = j0 + wn + nt * 16 + r16;
    float bias = b2[col];
#pragma unroll
    for (int mt = 0; mt < 4; ++mt) {
      int rbase = i0 + wm + mt * 16 + quad * 4;
#pragma unroll
      for (int r = 0; r < 4; ++r) {
        size_t idx = (size_t)(rbase + r) * DIMD + col;
        out[idx] = ifeats[idx] + bias + acc[mt][nt][r];
      }
    }
  }
}

// ---------------------------------------------------------------------------
extern "C" void kernel_launch(void* const* d_in, const int* in_sizes, int n_in,
                              void* d_out, int out_size, void* d_ws, size_t ws_size,
                              hipStream_t stream) {
  const float* ifeats = (const float*)d_in[0];
  const float* tn     = (const float*)d_in[1];
  const float* ta     = (const float*)d_in[2];
  const float* cw     = (const float*)d_in[3];
  const float* cb     = (const float*)d_in[4];
  const float* w2     = (const float*)d_in[5];
  const float* b2     = (const float*)d_in[6];
  float* out = (float*)d_out;

  // ws: [0, 4MB) w2 bf16 | [4MB, 36MB) x2 bf16
  u16* w2b = (u16*)d_ws;
  u16* x2  = (u16*)((char*)d_ws + (size_t)DIMD * KDIM * 2);

  pre_kernel<<<NROWS + (DIMD * KDIM / 8) / 256, 256, 0, stream>>>(
      ifeats, tn, ta, cw, cb, w2, x2, w2b);
  gemm_bt<<<512, 256, 0, stream>>>(x2, w2b, ifeats, b2, out);
}